// Round 12
// baseline (315.801 us; speedup 1.0000x reference)
//
#include <hip/hip_runtime.h>

#define N_NODES 100000
#define N_EDGES 1600000
#define IN_DIM 32
#define HID_DIM 64
#define OUT_DIM 8
#define XH 16                        // half of IN_DIM
#define CAP 64                       // slots per node; P(deg>64)~1e-18 (Poisson 16)
#define CHUNK 4096                   // edges per k_part block
#define NCHUNK ((N_EDGES + CHUNK - 1) / CHUNK)   // 391
#define RBLK 64                      // repack blocks appended to k_part
#define SLICE_W (N_NODES / 8)        // 12500
#define QCAP 262144                  // per-slice queue capacity

typedef unsigned short u16;
typedef unsigned int u32;
typedef unsigned long long ull;

__device__ __forceinline__ float bf2f(u16 v) {
    return __uint_as_float(((u32)v) << 16);
}

__device__ __forceinline__ u16 f2bf(float f) {
    u32 u = __float_as_uint(f);
    u32 lsb = (u >> 16) & 1u;
    u += 0x7fffu + lsb;
    return (u16)(u >> 16);
}

__device__ __forceinline__ float ldf(const void* p, size_t i, int bf) {
    return bf ? bf2f(((const u16*)p)[i]) : ((const float*)p)[i];
}

// ---- Phase A: probe (per block) + weight transpose (block 0) +
//      x repack to bf16 halves (blocks NCHUNK..NCHUNK+RBLK-1) +
//      edge partition into 8 per-slice queues (blocks 0..NCHUNK-1). ----
__global__ __launch_bounds__(256) void k_part(
    const int* __restrict__ ei, const u32* __restrict__ xw,
    const void* __restrict__ x,
    const void* __restrict__ W1l, const void* __restrict__ b1,
    const void* __restrict__ W1r,
    const void* __restrict__ W2l, const void* __restrict__ b2,
    const void* __restrict__ W2r,
    int* __restrict__ qcnt, u32* __restrict__ qbuf,
    float* __restrict__ tW1l, float* __restrict__ tW1r,
    float* __restrict__ tW2l, float* __restrict__ tW2r,
    float* __restrict__ tb1, float* __restrict__ tb2,
    u16* __restrict__ xlo, u16* __restrict__ xhi)
{
    __shared__ int shv, bfv;
    __shared__ int hist[4][8], wbase[4][8], lcur[4][8], gbase[8];
    int t = threadIdx.x, w = t >> 6;
    if (t < 64) {   // proven dtype probe, executed per block (same data)
        int v = ei[2 * t + 1];
        ull m1 = __ballot(v == 0);
        u32 wd = xw[t];
        u32 b = (wd >> 8) & 0x7fu;
        ull m2 = __ballot(b >= 0x38u && b <= 0x41u);
        if (t == 0) {
            shv = (m1 == ~0ULL) ? 1 : 0;
            bfv = (__popcll(m2) >= 56) ? 1 : 0;
        }
    }
    if (t < 32) { hist[t >> 3][t & 7] = 0; lcur[t >> 3][t & 7] = 0; }
    __syncthreads();
    int sh = shv, bf = bfv;

    if (blockIdx.x >= NCHUNK) {   // repack duty: x -> bf16 lo/hi halves
        for (int i = (blockIdx.x - NCHUNK) * 256 + t; i < N_NODES * XH;
             i += RBLK * 256) {
            int node = i >> 4, d = i & 15;
            xlo[i] = f2bf(ldf(x, (size_t)node * IN_DIM + d, bf));
            xhi[i] = f2bf(ldf(x, (size_t)node * IN_DIM + XH + d, bf));
        }
        return;
    }
    if (blockIdx.x == 0) {        // weight transpose duty (f32 into ws)
        for (int i = t; i < HID_DIM * IN_DIM; i += 256) {
            int o = i / IN_DIM, k = i % IN_DIM;
            tW1l[k * HID_DIM + o] = ldf(W1l, i, bf);
            tW1r[k * HID_DIM + o] = ldf(W1r, i, bf);
        }
        for (int i = t; i < OUT_DIM * HID_DIM; i += 256) {
            int o = i / HID_DIM, k = i % HID_DIM;
            tW2l[k * OUT_DIM + o] = ldf(W2l, i, bf);
            tW2r[k * OUT_DIM + o] = ldf(W2r, i, bf);
        }
        if (t < HID_DIM) tb1[t] = ldf(b1, t, bf);
        if (t < OUT_DIM) tb2[t] = ldf(b2, t, bf);
    }

    // edge partition (R10-proven)
    int e0 = blockIdx.x * CHUNK;
    int myd[16], mys[16];
    #pragma unroll
    for (int i = 0; i < 16; i++) {
        int e = e0 + i * 256 + t;
        if (e < N_EDGES) {
            size_t off = (size_t)e << sh;
            mys[i] = ei[off];
            int d = ei[((size_t)N_EDGES << sh) + off];
            myd[i] = d;
            atomicAdd(&hist[w][d / SLICE_W], 1);
        } else myd[i] = -1;
    }
    __syncthreads();
    if (t < 8) {
        int tot = hist[0][t] + hist[1][t] + hist[2][t] + hist[3][t];
        gbase[t] = atomicAdd(&qcnt[t], tot);
    }
    __syncthreads();
    if (t < 32) {
        int w2 = t >> 3, s = t & 7;
        int p = gbase[s];
        for (int w3 = 0; w3 < w2; w3++) p += hist[w3][s];
        wbase[w2][s] = p;
    }
    __syncthreads();
    #pragma unroll
    for (int i = 0; i < 16; i++) {
        int d = myd[i];
        if (d >= 0) {
            int s = d / SLICE_W;
            int p = wbase[w][s] + atomicAdd(&lcur[w][s], 1);
            qbuf[(size_t)s * QCAP + p] = ((u32)mys[i] << 14) | (u32)(d - s * SLICE_W);
        }
    }
}

// ---- Phase B: build slot table from queues (R10-proven, flags dropped). ----
__global__ __launch_bounds__(256) void k_build2(
    const int* __restrict__ qcnt, const u32* __restrict__ qbuf,
    int* __restrict__ cnt, int* __restrict__ slot)
{
    int slice = blockIdx.x & 7, bi = blockIdx.x >> 3;
    int m = qcnt[slice];
    int lo = slice * SLICE_W;
    const u32* q = qbuf + (size_t)slice * QCAP;
    for (int i = bi * 256 + threadIdx.x; i < m; i += 64 * 256) {
        u32 u = q[i];
        int d = lo + (int)(u & 0x3FFFu);
        int s = (int)(u >> 14);
        int pos = atomicAdd(&cnt[d], 1);
        if (pos < CAP) slot[(size_t)d * CAP + pos] = s;
    }
}

// ---- Gather pass A: agglo[n][0:16] = sum over neighbors of xlo.
//      2 nodes/wave, 8/block; R8-proven 2-way-ILP loop; rows 32B from
//      3.2MB L2-resident xlo. No LDS beyond trivial; no dtype branches. ----
__global__ __launch_bounds__(256, 8) void k_sage1a(
    const u16* __restrict__ xlo, const int* __restrict__ cnt,
    const int* __restrict__ slot, float* __restrict__ agglo)
{
    int t = threadIdx.x;
    int wid = t >> 6, lane = t & 63;
    int half = lane >> 5;
    int g2 = (lane >> 3) & 3;
    int l = lane & 7;                // 2-dim chunk index (dims 2l, 2l+1)
    int ns = wid * 2 + half;
    int n = blockIdx.x * 8 + ns;
    int deg = cnt[n];
    int cl = (deg < CAP) ? deg : CAP;
    const int* srow = slot + (size_t)n * CAP;

    float a0 = 0, a1 = 0, c0 = 0, c1 = 0;
    int j = g2;
    for (; j + 4 < cl; j += 8) {
        int sA = srow[j];
        int sB = srow[j + 4];
        ushort2 vA = reinterpret_cast<const ushort2*>(xlo + (size_t)sA * XH)[l];
        ushort2 vB = reinterpret_cast<const ushort2*>(xlo + (size_t)sB * XH)[l];
        a0 += bf2f(vA.x); a1 += bf2f(vA.y);
        c0 += bf2f(vB.x); c1 += bf2f(vB.y);
    }
    if (j < cl) {
        int s = srow[j];
        ushort2 v = reinterpret_cast<const ushort2*>(xlo + (size_t)s * XH)[l];
        a0 += bf2f(v.x); a1 += bf2f(v.y);
    }
    a0 += c0; a1 += c1;
    a0 += __shfl_xor(a0, 8, 64);  a0 += __shfl_xor(a0, 16, 64);
    a1 += __shfl_xor(a1, 8, 64);  a1 += __shfl_xor(a1, 16, 64);
    if (g2 == 0) {
        agglo[(size_t)n * XH + 2 * l + 0] = a0;
        agglo[(size_t)n * XH + 2 * l + 1] = a1;
    }
}

// ---- Gather pass B: hi-half gather + combine + dense L1 + L2 projections. ----
__global__ __launch_bounds__(256, 8) void k_sage1b(
    const u16* __restrict__ xlo, const u16* __restrict__ xhi,
    const float* __restrict__ agglo,
    const int* __restrict__ cnt, const int* __restrict__ slot,
    const float* __restrict__ tW1l, const float* __restrict__ tW1r,
    const float* __restrict__ tW2l, const float* __restrict__ tW2r,
    const float* __restrict__ tb1, const float* __restrict__ tb2,
    u16* __restrict__ gbuf, float* __restrict__ rbuf)
{
    __shared__ float aggbuf[8][IN_DIM];
    __shared__ float xbuf[8][IN_DIM];
    __shared__ float hbuf[8][HID_DIM + 1];

    int t = threadIdx.x;
    int wid = t >> 6, lane = t & 63;
    int half = lane >> 5;
    int g2 = (lane >> 3) & 3;
    int l = lane & 7;
    int ns = wid * 2 + half;
    int n = blockIdx.x * 8 + ns;
    int deg = cnt[n];
    int cl = (deg < CAP) ? deg : CAP;
    const int* srow = slot + (size_t)n * CAP;

    float a0 = 0, a1 = 0, c0 = 0, c1 = 0;
    int j = g2;
    for (; j + 4 < cl; j += 8) {
        int sA = srow[j];
        int sB = srow[j + 4];
        ushort2 vA = reinterpret_cast<const ushort2*>(xhi + (size_t)sA * XH)[l];
        ushort2 vB = reinterpret_cast<const ushort2*>(xhi + (size_t)sB * XH)[l];
        a0 += bf2f(vA.x); a1 += bf2f(vA.y);
        c0 += bf2f(vB.x); c1 += bf2f(vB.y);
    }
    if (j < cl) {
        int s = srow[j];
        ushort2 v = reinterpret_cast<const ushort2*>(xhi + (size_t)s * XH)[l];
        a0 += bf2f(v.x); a1 += bf2f(v.y);
    }
    a0 += c0; a1 += c1;
    a0 += __shfl_xor(a0, 8, 64);  a0 += __shfl_xor(a0, 16, 64);
    a1 += __shfl_xor(a1, 8, 64);  a1 += __shfl_xor(a1, 16, 64);
    if (g2 == 0) {        // hi-half neighbor sum
        aggbuf[ns][XH + 2 * l + 0] = a0;
        aggbuf[ns][XH + 2 * l + 1] = a1;
    } else if (g2 == 1) { // self row (both halves, bf16 exact round-trip)
        ushort2 lo = reinterpret_cast<const ushort2*>(xlo + (size_t)n * XH)[l];
        ushort2 hi = reinterpret_cast<const ushort2*>(xhi + (size_t)n * XH)[l];
        xbuf[ns][2 * l + 0] = bf2f(lo.x);  xbuf[ns][2 * l + 1] = bf2f(lo.y);
        xbuf[ns][XH + 2 * l + 0] = bf2f(hi.x);  xbuf[ns][XH + 2 * l + 1] = bf2f(hi.y);
    } else if (g2 == 2) { // lo-half neighbor sum from pass A (coalesced)
        float2 v = reinterpret_cast<const float2*>(agglo + (size_t)n * XH)[l];
        aggbuf[ns][2 * l + 0] = v.x;
        aggbuf[ns][2 * l + 1] = v.y;
    }
    __syncthreads();

    // dense layer 1 (R9-proven): lane computes output o=lane for both nodes
    float rd0 = 1.0f / fmaxf((float)__shfl(deg, 0, 64), 1.0f);
    float rd1 = 1.0f / fmaxf((float)__shfl(deg, 32, 64), 1.0f);
    int s0 = wid * 2, s1 = wid * 2 + 1;
    int o = lane;
    float bb = tb1[o];
    float acc0 = bb, acc1 = bb;
    #pragma unroll 8
    for (int k = 0; k < IN_DIM; k++) {
        float wl = tW1l[k * HID_DIM + o];
        float wr = tW1r[k * HID_DIM + o];
        acc0 += (aggbuf[s0][k] * rd0) * wl + xbuf[s0][k] * wr;
        acc1 += (aggbuf[s1][k] * rd1) * wl + xbuf[s1][k] * wr;
    }
    hbuf[s0][o] = fmaxf(acc0, 0.0f);
    hbuf[s1][o] = fmaxf(acc1, 0.0f);
    __syncthreads();

    // layer-2 projections: g = h@W2l^T (bf16-packed), r = h@W2r^T + b2
    float ga = 0.0f, ra = 0.0f;
    #pragma unroll 4
    for (int m = 0; m < 16; m++) {
        int k = g2 * 16 + m;
        float hv = hbuf[ns][k];
        ga += hv * tW2l[k * OUT_DIM + l];
        ra += hv * tW2r[k * OUT_DIM + l];
    }
    ga += __shfl_xor(ga, 8, 64);  ga += __shfl_xor(ga, 16, 64);
    ra += __shfl_xor(ra, 8, 64);  ra += __shfl_xor(ra, 16, 64);
    if (g2 == 0) {
        gbuf[(size_t)n * OUT_DIM + l] = f2bf(ga);
        rbuf[(size_t)n * OUT_DIM + l] = ra + tb2[l];
    }
}

// ---- Final: out[n] = mean(g_nbr) + r[n].  8 lanes/node, 4-way ILP
//      (R11-proven loop); gbuf bf16 (1.6MB, L2-resident). ----
__global__ __launch_bounds__(256) void k_sage3(
    const u16* __restrict__ gbuf, const float* __restrict__ rbuf,
    const int* __restrict__ cnt, const int* __restrict__ slot,
    const u32* __restrict__ xw, void* __restrict__ out)
{
    __shared__ int bfv;
    int t = threadIdx.x;
    if (t < 64) {   // output-dtype probe (proven)
        u32 w = xw[t];
        u32 b = (w >> 8) & 0x7fu;
        ull m2 = __ballot(b >= 0x38u && b <= 0x41u);
        if (t == 0) bfv = (__popcll(m2) >= 56) ? 1 : 0;
    }
    __syncthreads();
    int grp = t >> 3, l = t & 7;
    int n = blockIdx.x * 32 + grp;    // grid = N/32 exactly
    int deg = cnt[n];
    int cl = (deg < CAP) ? deg : CAP;
    const int* srow = slot + (size_t)n * CAP;
    float a0 = 0.0f, a1 = 0.0f, a2 = 0.0f, a3 = 0.0f;
    int j = 0;
    for (; j + 3 < cl; j += 4) {
        int v0 = srow[j];
        int v1 = srow[j + 1];
        int v2 = srow[j + 2];
        int v3 = srow[j + 3];
        a0 += bf2f(gbuf[(size_t)v0 * OUT_DIM + l]);
        a1 += bf2f(gbuf[(size_t)v1 * OUT_DIM + l]);
        a2 += bf2f(gbuf[(size_t)v2 * OUT_DIM + l]);
        a3 += bf2f(gbuf[(size_t)v3 * OUT_DIM + l]);
    }
    for (; j < cl; j++) a0 += bf2f(gbuf[(size_t)srow[j] * OUT_DIM + l]);
    float res = (a0 + a1 + a2 + a3) / fmaxf((float)deg, 1.0f)
              + rbuf[(size_t)n * OUT_DIM + l];
    size_t oi = (size_t)n * OUT_DIM + l;
    if (bfv) ((u16*)out)[oi] = f2bf(res);
    else     ((float*)out)[oi] = res;
}

extern "C" void kernel_launch(void* const* d_in, const int* in_sizes, int n_in,
                              void* d_out, int out_size, void* d_ws, size_t ws_size,
                              hipStream_t stream) {
    const void* x   = d_in[0];
    const int*  ei  = (const int*)d_in[1];
    const void* W1l = d_in[2];
    const void* b1  = d_in[3];
    const void* W1r = d_in[4];
    const void* W2l = d_in[5];
    const void* b2  = d_in[6];
    const void* W2r = d_in[7];

    // ws layout (4B units); total ~52 MB (ws >= 64.4 MB proven in round 2)
    int* cnt     = (int*)d_ws;                       // N
    int* qcnt    = cnt + N_NODES;                    // 8
    float* tW1l  = (float*)(qcnt + 8);               // 2048
    float* tW1r  = tW1l + IN_DIM * HID_DIM;          // 2048
    float* tW2l  = tW1r + IN_DIM * HID_DIM;          // 512
    float* tW2r  = tW2l + HID_DIM * OUT_DIM;         // 512
    float* tb1   = tW2r + HID_DIM * OUT_DIM;         // 64
    float* tb2   = tb1 + HID_DIM;                    // 8
    int* slot    = (int*)(tb2 + OUT_DIM);            // N*CAP (25.6 MB)
    u32* qbuf    = (u32*)(slot + (size_t)N_NODES * CAP);    // 8*QCAP (8 MB)
    u16* xlo     = (u16*)(qbuf + (size_t)8 * QCAP);         // N*16 u16 (3.2 MB)
    u16* xhi     = xlo + (size_t)N_NODES * XH;              // N*16 u16 (3.2 MB)
    float* agglo = (float*)(xhi + (size_t)N_NODES * XH);    // N*16 f32 (6.4 MB)
    u16* gbuf    = (u16*)(agglo + (size_t)N_NODES * XH);    // N*8 u16 (1.6 MB)
    float* rbuf  = (float*)(gbuf + (size_t)N_NODES * OUT_DIM); // N*8 f32 (3.2 MB)

    // zero cnt + qcnt (0.4 MB)
    hipMemsetAsync(d_ws, 0, (size_t)(N_NODES + 8) * sizeof(int), stream);

    k_part<<<NCHUNK + RBLK, 256, 0, stream>>>(
        ei, (const u32*)x, x, W1l, b1, W1r, W2l, b2, W2r,
        qcnt, qbuf, tW1l, tW1r, tW2l, tW2r, tb1, tb2, xlo, xhi);
    k_build2<<<512, 256, 0, stream>>>(qcnt, qbuf, cnt, slot);
    k_sage1a<<<N_NODES / 8, 256, 0, stream>>>(xlo, cnt, slot, agglo);
    k_sage1b<<<N_NODES / 8, 256, 0, stream>>>(xlo, xhi, agglo, cnt, slot,
                                              tW1l, tW1r, tW2l, tW2r, tb1, tb2,
                                              gbuf, rbuf);
    k_sage3<<<N_NODES / 32, 256, 0, stream>>>(gbuf, rbuf, cnt, slot,
                                              (const u32*)x, d_out);
}

// Round 13
// 253.212 us; speedup vs baseline: 1.2472x; 1.2472x over previous
//
#include <hip/hip_runtime.h>

#define N_NODES 100000
#define N_EDGES 1600000
#define IN_DIM 32
#define HID_DIM 64
#define OUT_DIM 8
#define CAP 64                       // slots per node; P(deg>64)~1e-18 (Poisson 16)
#define CHUNK 4096                   // edges per k_part block
#define NCHUNK ((N_EDGES + CHUNK - 1) / CHUNK)   // 391
#define SLICE_W (N_NODES / 8)        // 12500
#define QCAP 262144                  // per-slice queue capacity

typedef unsigned short u16;
typedef unsigned int u32;
typedef unsigned long long ull;

__device__ __forceinline__ float bf2f(u16 v) {
    return __uint_as_float(((u32)v) << 16);
}

__device__ __forceinline__ u16 f2bf(float f) {
    u32 u = __float_as_uint(f);
    u32 lsb = (u >> 16) & 1u;
    u += 0x7fffu + lsb;
    return (u16)(u >> 16);
}

__device__ __forceinline__ float ldf(const void* p, size_t i, int bf) {
    return bf ? bf2f(((const u16*)p)[i]) : ((const float*)p)[i];
}

// ---- Phase A: per-block dtype probe + cnt zeroing + weight transpose
//      (blocks 0..15, grid-strided) + edge partition into 8 per-slice
//      queues (R10/R11-proven loop). ----
__global__ __launch_bounds__(256) void k_part(
    const int* __restrict__ ei, const u32* __restrict__ xw,
    const void* __restrict__ W1l, const void* __restrict__ b1,
    const void* __restrict__ W1r,
    const void* __restrict__ W2l, const void* __restrict__ b2,
    const void* __restrict__ W2r,
    int* __restrict__ qcnt, u32* __restrict__ qbuf,
    int* __restrict__ cnt,
    float* __restrict__ tW1l, float* __restrict__ tW1r,
    float* __restrict__ tW2l, float* __restrict__ tW2r,
    float* __restrict__ tb1, float* __restrict__ tb2)
{
    __shared__ int shv, bfv;
    __shared__ int hist[4][8], wbase[4][8], lcur[4][8], gbase[8];
    int t = threadIdx.x, w = t >> 6;
    if (t < 64) {   // proven dtype probe, executed per block (same data)
        int v = ei[2 * t + 1];
        ull m1 = __ballot(v == 0);
        u32 wd = xw[t];
        u32 b = (wd >> 8) & 0x7fu;
        ull m2 = __ballot(b >= 0x38u && b <= 0x41u);
        if (t == 0) {
            shv = (m1 == ~0ULL) ? 1 : 0;
            bfv = (__popcll(m2) >= 56) ? 1 : 0;
        }
    }
    if (t < 32) { hist[t >> 3][t & 7] = 0; lcur[t >> 3][t & 7] = 0; }
    __syncthreads();
    int sh = shv, bf = bfv;

    // zero cnt for k_build2 (runs after this kernel completes; stream-ordered)
    for (int i = blockIdx.x * 256 + t; i < N_NODES; i += NCHUNK * 256) cnt[i] = 0;

    if (blockIdx.x < 16) {        // weight transpose duty (R11-proven indexing)
        for (int i = blockIdx.x * 256 + t; i < HID_DIM * IN_DIM; i += 16 * 256) {
            int o = i / IN_DIM, k = i % IN_DIM;
            tW1l[k * HID_DIM + o] = ldf(W1l, i, bf);
            tW1r[k * HID_DIM + o] = ldf(W1r, i, bf);
        }
        for (int i = blockIdx.x * 256 + t; i < OUT_DIM * HID_DIM; i += 16 * 256) {
            int o = i / HID_DIM, k = i % HID_DIM;
            tW2l[k * OUT_DIM + o] = ldf(W2l, i, bf);
            tW2r[k * OUT_DIM + o] = ldf(W2r, i, bf);
        }
        if (blockIdx.x == 0) {
            if (t < HID_DIM) tb1[t] = ldf(b1, t, bf);
            if (t < OUT_DIM) tb2[t] = ldf(b2, t, bf);
        }
    }

    // edge partition (R10-proven)
    int e0 = blockIdx.x * CHUNK;
    int myd[16], mys[16];
    #pragma unroll
    for (int i = 0; i < 16; i++) {
        int e = e0 + i * 256 + t;
        if (e < N_EDGES) {
            size_t off = (size_t)e << sh;
            mys[i] = ei[off];
            int d = ei[((size_t)N_EDGES << sh) + off];
            myd[i] = d;
            atomicAdd(&hist[w][d / SLICE_W], 1);
        } else myd[i] = -1;
    }
    __syncthreads();
    if (t < 8) {
        int tot = hist[0][t] + hist[1][t] + hist[2][t] + hist[3][t];
        gbase[t] = atomicAdd(&qcnt[t], tot);
    }
    __syncthreads();
    if (t < 32) {
        int w2 = t >> 3, s = t & 7;
        int p = gbase[s];
        for (int w3 = 0; w3 < w2; w3++) p += hist[w3][s];
        wbase[w2][s] = p;
    }
    __syncthreads();
    #pragma unroll
    for (int i = 0; i < 16; i++) {
        int d = myd[i];
        if (d >= 0) {
            int s = d / SLICE_W;
            int p = wbase[w][s] + atomicAdd(&lcur[w][s], 1);
            qbuf[(size_t)s * QCAP + p] = ((u32)mys[i] << 14) | (u32)(d - s * SLICE_W);
        }
    }
}

// ---- Phase B: build slot table from queues (R10-proven). ----
__global__ __launch_bounds__(256) void k_build2(
    const int* __restrict__ qcnt, const u32* __restrict__ qbuf,
    int* __restrict__ cnt, int* __restrict__ slot)
{
    int slice = blockIdx.x & 7, bi = blockIdx.x >> 3;
    int m = qcnt[slice];
    int lo = slice * SLICE_W;
    const u32* q = qbuf + (size_t)slice * QCAP;
    for (int i = bi * 256 + threadIdx.x; i < m; i += 64 * 256) {
        u32 u = q[i];
        int d = lo + (int)(u & 0x3FFFu);
        int s = (int)(u >> 14);
        int pos = atomicAdd(&cnt[d], 1);
        if (pos < CAP) slot[(size_t)d * CAP + pos] = s;
    }
}

// ---- Fused layer 1 + layer-2 projections. 2 nodes/wave, 8/block.
//      R11-proven gather (4-way + 2-way remainder); epilogue writes
//      gbuf as bf16 (R12-proven piece). ----
__global__ __launch_bounds__(256, 8) void k_sage1(
    const void* __restrict__ x, const int* __restrict__ cnt,
    const int* __restrict__ slot,
    const float* __restrict__ tW1l, const float* __restrict__ tW1r,
    const float* __restrict__ tW2l, const float* __restrict__ tW2r,
    const float* __restrict__ tb1, const float* __restrict__ tb2,
    const int* __restrict__ flags_unused,
    u16* __restrict__ gbuf, float* __restrict__ rbuf,
    const u32* __restrict__ xw)
{
    __shared__ float aggbuf[8][IN_DIM];
    __shared__ float xbuf[8][IN_DIM];
    __shared__ float hbuf[8][HID_DIM + 1];          // pad 65
    __shared__ int bfv;

    int t = threadIdx.x;
    if (t < 64) {   // dtype probe (proven)
        u32 wd = xw[t];
        u32 b = (wd >> 8) & 0x7fu;
        ull m2 = __ballot(b >= 0x38u && b <= 0x41u);
        if (t == 0) bfv = (__popcll(m2) >= 56) ? 1 : 0;
    }
    __syncthreads();
    int bf = bfv;
    int wid = t >> 6, lane = t & 63;
    int half = lane >> 5;            // node within the wave's pair
    int g2 = (lane >> 3) & 3;        // 4 neighbor-groups per node
    int l = lane & 7;                // 4-dim chunk index within row
    int ns = wid * 2 + half;         // node slot 0..7
    int n = blockIdx.x * 8 + ns;     // grid = N/8 exactly
    int deg = cnt[n];
    int cl = (deg < CAP) ? deg : CAP;
    const int* srow = slot + (size_t)n * CAP;

    float a0 = 0, a1 = 0, a2 = 0, a3 = 0;
    float c0 = 0, c1 = 0, c2 = 0, c3 = 0;
    float d0 = 0, d1 = 0, d2 = 0, d3 = 0;
    float e0 = 0, e1 = 0, e2 = 0, e3 = 0;
    int j = g2;
    for (; j + 12 < cl; j += 16) {   // 4 independent neighbor loads in flight
        int sA = srow[j];
        int sB = srow[j + 4];
        int sC = srow[j + 8];
        int sD = srow[j + 12];
        if (bf) {
            ushort4 vA = reinterpret_cast<const ushort4*>((const u16*)x + (size_t)sA * IN_DIM)[l];
            ushort4 vB = reinterpret_cast<const ushort4*>((const u16*)x + (size_t)sB * IN_DIM)[l];
            ushort4 vC = reinterpret_cast<const ushort4*>((const u16*)x + (size_t)sC * IN_DIM)[l];
            ushort4 vD = reinterpret_cast<const ushort4*>((const u16*)x + (size_t)sD * IN_DIM)[l];
            a0 += bf2f(vA.x); a1 += bf2f(vA.y); a2 += bf2f(vA.z); a3 += bf2f(vA.w);
            c0 += bf2f(vB.x); c1 += bf2f(vB.y); c2 += bf2f(vB.z); c3 += bf2f(vB.w);
            d0 += bf2f(vC.x); d1 += bf2f(vC.y); d2 += bf2f(vC.z); d3 += bf2f(vC.w);
            e0 += bf2f(vD.x); e1 += bf2f(vD.y); e2 += bf2f(vD.z); e3 += bf2f(vD.w);
        } else {
            float4 vA = reinterpret_cast<const float4*>((const float*)x + (size_t)sA * IN_DIM)[l];
            float4 vB = reinterpret_cast<const float4*>((const float*)x + (size_t)sB * IN_DIM)[l];
            float4 vC = reinterpret_cast<const float4*>((const float*)x + (size_t)sC * IN_DIM)[l];
            float4 vD = reinterpret_cast<const float4*>((const float*)x + (size_t)sD * IN_DIM)[l];
            a0 += vA.x; a1 += vA.y; a2 += vA.z; a3 += vA.w;
            c0 += vB.x; c1 += vB.y; c2 += vB.z; c3 += vB.w;
            d0 += vC.x; d1 += vC.y; d2 += vC.z; d3 += vC.w;
            e0 += vD.x; e1 += vD.y; e2 += vD.z; e3 += vD.w;
        }
    }
    for (; j + 4 < cl; j += 8) {     // 2-way remainder (R8-proven)
        int sA = srow[j];
        int sB = srow[j + 4];
        if (bf) {
            ushort4 vA = reinterpret_cast<const ushort4*>((const u16*)x + (size_t)sA * IN_DIM)[l];
            ushort4 vB = reinterpret_cast<const ushort4*>((const u16*)x + (size_t)sB * IN_DIM)[l];
            a0 += bf2f(vA.x); a1 += bf2f(vA.y); a2 += bf2f(vA.z); a3 += bf2f(vA.w);
            c0 += bf2f(vB.x); c1 += bf2f(vB.y); c2 += bf2f(vB.z); c3 += bf2f(vB.w);
        } else {
            float4 vA = reinterpret_cast<const float4*>((const float*)x + (size_t)sA * IN_DIM)[l];
            float4 vB = reinterpret_cast<const float4*>((const float*)x + (size_t)sB * IN_DIM)[l];
            a0 += vA.x; a1 += vA.y; a2 += vA.z; a3 += vA.w;
            c0 += vB.x; c1 += vB.y; c2 += vB.z; c3 += vB.w;
        }
    }
    if (j < cl) {                    // tail (at most one per group)
        int s = srow[j];
        if (bf) {
            ushort4 v = reinterpret_cast<const ushort4*>((const u16*)x + (size_t)s * IN_DIM)[l];
            a0 += bf2f(v.x); a1 += bf2f(v.y); a2 += bf2f(v.z); a3 += bf2f(v.w);
        } else {
            float4 v = reinterpret_cast<const float4*>((const float*)x + (size_t)s * IN_DIM)[l];
            a0 += v.x; a1 += v.y; a2 += v.z; a3 += v.w;
        }
    }
    a0 += c0 + d0 + e0;
    a1 += c1 + d1 + e1;
    a2 += c2 + d2 + e2;
    a3 += c3 + d3 + e3;
    a0 += __shfl_xor(a0, 8, 64);  a0 += __shfl_xor(a0, 16, 64);
    a1 += __shfl_xor(a1, 8, 64);  a1 += __shfl_xor(a1, 16, 64);
    a2 += __shfl_xor(a2, 8, 64);  a2 += __shfl_xor(a2, 16, 64);
    a3 += __shfl_xor(a3, 8, 64);  a3 += __shfl_xor(a3, 16, 64);
    if (g2 == 0) {
        aggbuf[ns][4 * l + 0] = a0; aggbuf[ns][4 * l + 1] = a1;
        aggbuf[ns][4 * l + 2] = a2; aggbuf[ns][4 * l + 3] = a3;
    } else if (g2 == 1) {   // self row
        float f0, f1, f2, f3;
        if (bf) {
            ushort4 v = reinterpret_cast<const ushort4*>((const u16*)x + (size_t)n * IN_DIM)[l];
            f0 = bf2f(v.x); f1 = bf2f(v.y); f2 = bf2f(v.z); f3 = bf2f(v.w);
        } else {
            float4 v = reinterpret_cast<const float4*>((const float*)x + (size_t)n * IN_DIM)[l];
            f0 = v.x; f1 = v.y; f2 = v.z; f3 = v.w;
        }
        xbuf[ns][4 * l + 0] = f0; xbuf[ns][4 * l + 1] = f1;
        xbuf[ns][4 * l + 2] = f2; xbuf[ns][4 * l + 3] = f3;
    }
    __syncthreads();

    // dense layer 1: each lane computes output o=lane for BOTH nodes of its wave.
    float rd0 = 1.0f / fmaxf((float)__shfl(deg, 0, 64), 1.0f);
    float rd1 = 1.0f / fmaxf((float)__shfl(deg, 32, 64), 1.0f);
    int s0 = wid * 2, s1 = wid * 2 + 1;
    int o = lane;
    float bb = tb1[o];
    float acc0 = bb, acc1 = bb;
    #pragma unroll 8
    for (int k = 0; k < IN_DIM; k++) {
        float wl = tW1l[k * HID_DIM + o];
        float wr = tW1r[k * HID_DIM + o];
        acc0 += (aggbuf[s0][k] * rd0) * wl + xbuf[s0][k] * wr;
        acc1 += (aggbuf[s1][k] * rd1) * wl + xbuf[s1][k] * wr;
    }
    hbuf[s0][o] = fmaxf(acc0, 0.0f);
    hbuf[s1][o] = fmaxf(acc1, 0.0f);
    __syncthreads();

    // layer-2 projections: g = h@W2l^T (bf16-packed), r = h@W2r^T + b2
    float ga = 0.0f, ra = 0.0f;
    #pragma unroll 4
    for (int m = 0; m < 16; m++) {
        int k = g2 * 16 + m;
        float hv = hbuf[ns][k];
        ga += hv * tW2l[k * OUT_DIM + l];
        ra += hv * tW2r[k * OUT_DIM + l];
    }
    ga += __shfl_xor(ga, 8, 64);  ga += __shfl_xor(ga, 16, 64);
    ra += __shfl_xor(ra, 8, 64);  ra += __shfl_xor(ra, 16, 64);
    if (g2 == 0) {
        gbuf[(size_t)n * OUT_DIM + l] = f2bf(ga);
        rbuf[(size_t)n * OUT_DIM + l] = ra + tb2[l];
    }
}

// ---- Final: out[n] = mean(g_nbr) + r[n]. 8 lanes/node, 4-way ILP
//      (R11-proven loop); gbuf bf16 (1.6MB L2-resident, R12-proven piece). ----
__global__ __launch_bounds__(256) void k_sage3(
    const u16* __restrict__ gbuf, const float* __restrict__ rbuf,
    const int* __restrict__ cnt, const int* __restrict__ slot,
    const u32* __restrict__ xw, void* __restrict__ out)
{
    __shared__ int bfv;
    int t = threadIdx.x;
    if (t < 64) {   // output-dtype probe (proven)
        u32 w = xw[t];
        u32 b = (w >> 8) & 0x7fu;
        ull m2 = __ballot(b >= 0x38u && b <= 0x41u);
        if (t == 0) bfv = (__popcll(m2) >= 56) ? 1 : 0;
    }
    __syncthreads();
    int grp = t >> 3, l = t & 7;
    int n = blockIdx.x * 32 + grp;    // grid = N/32 exactly
    int deg = cnt[n];
    int cl = (deg < CAP) ? deg : CAP;
    const int* srow = slot + (size_t)n * CAP;
    float a0 = 0.0f, a1 = 0.0f, a2 = 0.0f, a3 = 0.0f;
    int j = 0;
    for (; j + 3 < cl; j += 4) {
        int v0 = srow[j];
        int v1 = srow[j + 1];
        int v2 = srow[j + 2];
        int v3 = srow[j + 3];
        a0 += bf2f(gbuf[(size_t)v0 * OUT_DIM + l]);
        a1 += bf2f(gbuf[(size_t)v1 * OUT_DIM + l]);
        a2 += bf2f(gbuf[(size_t)v2 * OUT_DIM + l]);
        a3 += bf2f(gbuf[(size_t)v3 * OUT_DIM + l]);
    }
    for (; j < cl; j++) a0 += bf2f(gbuf[(size_t)srow[j] * OUT_DIM + l]);
    float res = (a0 + a1 + a2 + a3) / fmaxf((float)deg, 1.0f)
              + rbuf[(size_t)n * OUT_DIM + l];
    size_t oi = (size_t)n * OUT_DIM + l;
    if (bfv) ((u16*)out)[oi] = f2bf(res);
    else     ((float*)out)[oi] = res;
}

extern "C" void kernel_launch(void* const* d_in, const int* in_sizes, int n_in,
                              void* d_out, int out_size, void* d_ws, size_t ws_size,
                              hipStream_t stream) {
    const void* x   = d_in[0];
    const int*  ei  = (const int*)d_in[1];
    const void* W1l = d_in[2];
    const void* b1  = d_in[3];
    const void* W1r = d_in[4];
    const void* W2l = d_in[5];
    const void* b2  = d_in[6];
    const void* W2r = d_in[7];

    // ws layout (4B units); total ~40 MB (ws >= 64.4 MB proven in round 2)
    int* qcnt    = (int*)d_ws;                       // 8  (memset target)
    int* cnt     = qcnt + 8;                         // N  (zeroed by k_part)
    float* tW1l  = (float*)(cnt + N_NODES);          // 2048
    float* tW1r  = tW1l + IN_DIM * HID_DIM;          // 2048
    float* tW2l  = tW1r + IN_DIM * HID_DIM;          // 512
    float* tW2r  = tW2l + HID_DIM * OUT_DIM;         // 512
    float* tb1   = tW2r + HID_DIM * OUT_DIM;         // 64
    float* tb2   = tb1 + HID_DIM;                    // 8
    int* slot    = (int*)(tb2 + OUT_DIM);            // N*CAP (25.6 MB)
    u32* qbuf    = (u32*)(slot + (size_t)N_NODES * CAP);       // 8*QCAP (8 MB)
    u16* gbuf    = (u16*)(qbuf + (size_t)8 * QCAP);            // N*8 u16 (1.6 MB)
    float* rbuf  = (float*)(gbuf + (size_t)N_NODES * OUT_DIM); // N*8 f32 (3.2 MB)

    // zero qcnt only (32 B); cnt is zeroed inside k_part
    hipMemsetAsync(d_ws, 0, 8 * sizeof(int), stream);

    k_part<<<NCHUNK, 256, 0, stream>>>(ei, (const u32*)x,
                                       W1l, b1, W1r, W2l, b2, W2r,
                                       qcnt, qbuf, cnt,
                                       tW1l, tW1r, tW2l, tW2r, tb1, tb2);
    k_build2<<<512, 256, 0, stream>>>(qcnt, qbuf, cnt, slot);
    k_sage1<<<N_NODES / 8, 256, 0, stream>>>(x, cnt, slot, tW1l, tW1r,
                                             tW2l, tW2r, tb1, tb2, nullptr,
                                             gbuf, rbuf, (const u32*)x);
    k_sage3<<<N_NODES / 32, 256, 0, stream>>>(gbuf, rbuf, cnt, slot,
                                              (const u32*)x, d_out);
}

// Round 14
// 251.589 us; speedup vs baseline: 1.2552x; 1.0065x over previous
//
#include <hip/hip_runtime.h>

#define N_NODES 100000
#define N_EDGES 1600000
#define IN_DIM 32
#define HID_DIM 64
#define OUT_DIM 8
#define CAP 64                       // slots per node; P(deg>64)~1e-18 (Poisson 16)
#define CHUNK 4096                   // edges per k_part block
#define NCHUNK ((N_EDGES + CHUNK - 1) / CHUNK)   // 391
#define SLICE_W (N_NODES / 8)        // 12500
#define QCAP 262144                  // per-slice queue capacity
#define BBLK 2048                    // k_build2 grid (256 blocks/slice)

typedef unsigned short u16;
typedef unsigned int u32;
typedef unsigned long long ull;

__device__ __forceinline__ float bf2f(u16 v) {
    return __uint_as_float(((u32)v) << 16);
}

__device__ __forceinline__ u16 f2bf(float f) {
    u32 u = __float_as_uint(f);
    u32 lsb = (u >> 16) & 1u;
    u += 0x7fffu + lsb;
    return (u16)(u >> 16);
}

__device__ __forceinline__ float ldf(const void* p, size_t i, int bf) {
    return bf ? bf2f(((const u16*)p)[i]) : ((const float*)p)[i];
}

// ---- Phase A: per-block dtype probe + cnt zeroing + weight transpose
//      (blocks 0..15, grid-strided) + edge partition into 8 per-slice
//      queues (R10/R11-proven loop). ----
__global__ __launch_bounds__(256) void k_part(
    const int* __restrict__ ei, const u32* __restrict__ xw,
    const void* __restrict__ W1l, const void* __restrict__ b1,
    const void* __restrict__ W1r,
    const void* __restrict__ W2l, const void* __restrict__ b2,
    const void* __restrict__ W2r,
    int* __restrict__ qcnt, u32* __restrict__ qbuf,
    int* __restrict__ cnt,
    float* __restrict__ tW1l, float* __restrict__ tW1r,
    float* __restrict__ tW2l, float* __restrict__ tW2r,
    float* __restrict__ tb1, float* __restrict__ tb2)
{
    __shared__ int shv, bfv;
    __shared__ int hist[4][8], wbase[4][8], lcur[4][8], gbase[8];
    int t = threadIdx.x, w = t >> 6;
    if (t < 64) {   // proven dtype probe, executed per block (same data)
        int v = ei[2 * t + 1];
        ull m1 = __ballot(v == 0);
        u32 wd = xw[t];
        u32 b = (wd >> 8) & 0x7fu;
        ull m2 = __ballot(b >= 0x38u && b <= 0x41u);
        if (t == 0) {
            shv = (m1 == ~0ULL) ? 1 : 0;
            bfv = (__popcll(m2) >= 56) ? 1 : 0;
        }
    }
    if (t < 32) { hist[t >> 3][t & 7] = 0; lcur[t >> 3][t & 7] = 0; }
    __syncthreads();
    int sh = shv, bf = bfv;

    // zero cnt for k_build2 (runs after this kernel completes; stream-ordered)
    for (int i = blockIdx.x * 256 + t; i < N_NODES; i += NCHUNK * 256) cnt[i] = 0;

    if (blockIdx.x < 16) {        // weight transpose duty (R11-proven indexing)
        for (int i = blockIdx.x * 256 + t; i < HID_DIM * IN_DIM; i += 16 * 256) {
            int o = i / IN_DIM, k = i % IN_DIM;
            tW1l[k * HID_DIM + o] = ldf(W1l, i, bf);
            tW1r[k * HID_DIM + o] = ldf(W1r, i, bf);
        }
        for (int i = blockIdx.x * 256 + t; i < OUT_DIM * HID_DIM; i += 16 * 256) {
            int o = i / HID_DIM, k = i % HID_DIM;
            tW2l[k * OUT_DIM + o] = ldf(W2l, i, bf);
            tW2r[k * OUT_DIM + o] = ldf(W2r, i, bf);
        }
        if (blockIdx.x == 0) {
            if (t < HID_DIM) tb1[t] = ldf(b1, t, bf);
            if (t < OUT_DIM) tb2[t] = ldf(b2, t, bf);
        }
    }

    // edge partition (R10-proven)
    int e0 = blockIdx.x * CHUNK;
    int myd[16], mys[16];
    #pragma unroll
    for (int i = 0; i < 16; i++) {
        int e = e0 + i * 256 + t;
        if (e < N_EDGES) {
            size_t off = (size_t)e << sh;
            mys[i] = ei[off];
            int d = ei[((size_t)N_EDGES << sh) + off];
            myd[i] = d;
            atomicAdd(&hist[w][d / SLICE_W], 1);
        } else myd[i] = -1;
    }
    __syncthreads();
    if (t < 8) {
        int tot = hist[0][t] + hist[1][t] + hist[2][t] + hist[3][t];
        gbase[t] = atomicAdd(&qcnt[t], tot);
    }
    __syncthreads();
    if (t < 32) {
        int w2 = t >> 3, s = t & 7;
        int p = gbase[s];
        for (int w3 = 0; w3 < w2; w3++) p += hist[w3][s];
        wbase[w2][s] = p;
    }
    __syncthreads();
    #pragma unroll
    for (int i = 0; i < 16; i++) {
        int d = myd[i];
        if (d >= 0) {
            int s = d / SLICE_W;
            int p = wbase[w][s] + atomicAdd(&lcur[w][s], 1);
            qbuf[(size_t)s * QCAP + p] = ((u32)mys[i] << 14) | (u32)(d - s * SLICE_W);
        }
    }
}

// ---- Phase B: build slot table from queues (R10-proven loop body);
//      grid 2048 (256 blocks/slice) for 4x atomic/store concurrency. ----
__global__ __launch_bounds__(256) void k_build2(
    const int* __restrict__ qcnt, const u32* __restrict__ qbuf,
    int* __restrict__ cnt, int* __restrict__ slot)
{
    int slice = blockIdx.x & 7, bi = blockIdx.x >> 3;
    int m = qcnt[slice];
    int lo = slice * SLICE_W;
    const u32* q = qbuf + (size_t)slice * QCAP;
    for (int i = bi * 256 + threadIdx.x; i < m; i += (BBLK / 8) * 256) {
        u32 u = q[i];
        int d = lo + (int)(u & 0x3FFFu);
        int s = (int)(u >> 14);
        int pos = atomicAdd(&cnt[d], 1);
        if (pos < CAP) slot[(size_t)d * CAP + pos] = s;
    }
}

// ---- Fused layer 1 + layer-2 projections. 2 nodes/wave, 8/block.
//      R11-proven gather (4-way + 2-way remainder); epilogue writes
//      gbuf as bf16 (R12-proven piece). ----
__global__ __launch_bounds__(256, 8) void k_sage1(
    const void* __restrict__ x, const int* __restrict__ cnt,
    const int* __restrict__ slot,
    const float* __restrict__ tW1l, const float* __restrict__ tW1r,
    const float* __restrict__ tW2l, const float* __restrict__ tW2r,
    const float* __restrict__ tb1, const float* __restrict__ tb2,
    const int* __restrict__ flags_unused,
    u16* __restrict__ gbuf, float* __restrict__ rbuf,
    const u32* __restrict__ xw)
{
    __shared__ float aggbuf[8][IN_DIM];
    __shared__ float xbuf[8][IN_DIM];
    __shared__ float hbuf[8][HID_DIM + 1];          // pad 65
    __shared__ int bfv;

    int t = threadIdx.x;
    if (t < 64) {   // dtype probe (proven)
        u32 wd = xw[t];
        u32 b = (wd >> 8) & 0x7fu;
        ull m2 = __ballot(b >= 0x38u && b <= 0x41u);
        if (t == 0) bfv = (__popcll(m2) >= 56) ? 1 : 0;
    }
    __syncthreads();
    int bf = bfv;
    int wid = t >> 6, lane = t & 63;
    int half = lane >> 5;            // node within the wave's pair
    int g2 = (lane >> 3) & 3;        // 4 neighbor-groups per node
    int l = lane & 7;                // 4-dim chunk index within row
    int ns = wid * 2 + half;         // node slot 0..7
    int n = blockIdx.x * 8 + ns;     // grid = N/8 exactly
    int deg = cnt[n];
    int cl = (deg < CAP) ? deg : CAP;
    const int* srow = slot + (size_t)n * CAP;

    float a0 = 0, a1 = 0, a2 = 0, a3 = 0;
    float c0 = 0, c1 = 0, c2 = 0, c3 = 0;
    float d0 = 0, d1 = 0, d2 = 0, d3 = 0;
    float e0 = 0, e1 = 0, e2 = 0, e3 = 0;
    int j = g2;
    for (; j + 12 < cl; j += 16) {   // 4 independent neighbor loads in flight
        int sA = srow[j];
        int sB = srow[j + 4];
        int sC = srow[j + 8];
        int sD = srow[j + 12];
        if (bf) {
            ushort4 vA = reinterpret_cast<const ushort4*>((const u16*)x + (size_t)sA * IN_DIM)[l];
            ushort4 vB = reinterpret_cast<const ushort4*>((const u16*)x + (size_t)sB * IN_DIM)[l];
            ushort4 vC = reinterpret_cast<const ushort4*>((const u16*)x + (size_t)sC * IN_DIM)[l];
            ushort4 vD = reinterpret_cast<const ushort4*>((const u16*)x + (size_t)sD * IN_DIM)[l];
            a0 += bf2f(vA.x); a1 += bf2f(vA.y); a2 += bf2f(vA.z); a3 += bf2f(vA.w);
            c0 += bf2f(vB.x); c1 += bf2f(vB.y); c2 += bf2f(vB.z); c3 += bf2f(vB.w);
            d0 += bf2f(vC.x); d1 += bf2f(vC.y); d2 += bf2f(vC.z); d3 += bf2f(vC.w);
            e0 += bf2f(vD.x); e1 += bf2f(vD.y); e2 += bf2f(vD.z); e3 += bf2f(vD.w);
        } else {
            float4 vA = reinterpret_cast<const float4*>((const float*)x + (size_t)sA * IN_DIM)[l];
            float4 vB = reinterpret_cast<const float4*>((const float*)x + (size_t)sB * IN_DIM)[l];
            float4 vC = reinterpret_cast<const float4*>((const float*)x + (size_t)sC * IN_DIM)[l];
            float4 vD = reinterpret_cast<const float4*>((const float*)x + (size_t)sD * IN_DIM)[l];
            a0 += vA.x; a1 += vA.y; a2 += vA.z; a3 += vA.w;
            c0 += vB.x; c1 += vB.y; c2 += vB.z; c3 += vB.w;
            d0 += vC.x; d1 += vC.y; d2 += vC.z; d3 += vC.w;
            e0 += vD.x; e1 += vD.y; e2 += vD.z; e3 += vD.w;
        }
    }
    for (; j + 4 < cl; j += 8) {     // 2-way remainder (R8-proven)
        int sA = srow[j];
        int sB = srow[j + 4];
        if (bf) {
            ushort4 vA = reinterpret_cast<const ushort4*>((const u16*)x + (size_t)sA * IN_DIM)[l];
            ushort4 vB = reinterpret_cast<const ushort4*>((const u16*)x + (size_t)sB * IN_DIM)[l];
            a0 += bf2f(vA.x); a1 += bf2f(vA.y); a2 += bf2f(vA.z); a3 += bf2f(vA.w);
            c0 += bf2f(vB.x); c1 += bf2f(vB.y); c2 += bf2f(vB.z); c3 += bf2f(vB.w);
        } else {
            float4 vA = reinterpret_cast<const float4*>((const float*)x + (size_t)sA * IN_DIM)[l];
            float4 vB = reinterpret_cast<const float4*>((const float*)x + (size_t)sB * IN_DIM)[l];
            a0 += vA.x; a1 += vA.y; a2 += vA.z; a3 += vA.w;
            c0 += vB.x; c1 += vB.y; c2 += vB.z; c3 += vB.w;
        }
    }
    if (j < cl) {                    // tail (at most one per group)
        int s = srow[j];
        if (bf) {
            ushort4 v = reinterpret_cast<const ushort4*>((const u16*)x + (size_t)s * IN_DIM)[l];
            a0 += bf2f(v.x); a1 += bf2f(v.y); a2 += bf2f(v.z); a3 += bf2f(v.w);
        } else {
            float4 v = reinterpret_cast<const float4*>((const float*)x + (size_t)s * IN_DIM)[l];
            a0 += v.x; a1 += v.y; a2 += v.z; a3 += v.w;
        }
    }
    a0 += c0 + d0 + e0;
    a1 += c1 + d1 + e1;
    a2 += c2 + d2 + e2;
    a3 += c3 + d3 + e3;
    a0 += __shfl_xor(a0, 8, 64);  a0 += __shfl_xor(a0, 16, 64);
    a1 += __shfl_xor(a1, 8, 64);  a1 += __shfl_xor(a1, 16, 64);
    a2 += __shfl_xor(a2, 8, 64);  a2 += __shfl_xor(a2, 16, 64);
    a3 += __shfl_xor(a3, 8, 64);  a3 += __shfl_xor(a3, 16, 64);
    if (g2 == 0) {
        aggbuf[ns][4 * l + 0] = a0; aggbuf[ns][4 * l + 1] = a1;
        aggbuf[ns][4 * l + 2] = a2; aggbuf[ns][4 * l + 3] = a3;
    } else if (g2 == 1) {   // self row
        float f0, f1, f2, f3;
        if (bf) {
            ushort4 v = reinterpret_cast<const ushort4*>((const u16*)x + (size_t)n * IN_DIM)[l];
            f0 = bf2f(v.x); f1 = bf2f(v.y); f2 = bf2f(v.z); f3 = bf2f(v.w);
        } else {
            float4 v = reinterpret_cast<const float4*>((const float*)x + (size_t)n * IN_DIM)[l];
            f0 = v.x; f1 = v.y; f2 = v.z; f3 = v.w;
        }
        xbuf[ns][4 * l + 0] = f0; xbuf[ns][4 * l + 1] = f1;
        xbuf[ns][4 * l + 2] = f2; xbuf[ns][4 * l + 3] = f3;
    }
    __syncthreads();

    // dense layer 1: each lane computes output o=lane for BOTH nodes of its wave.
    float rd0 = 1.0f / fmaxf((float)__shfl(deg, 0, 64), 1.0f);
    float rd1 = 1.0f / fmaxf((float)__shfl(deg, 32, 64), 1.0f);
    int s0 = wid * 2, s1 = wid * 2 + 1;
    int o = lane;
    float bb = tb1[o];
    float acc0 = bb, acc1 = bb;
    #pragma unroll 8
    for (int k = 0; k < IN_DIM; k++) {
        float wl = tW1l[k * HID_DIM + o];
        float wr = tW1r[k * HID_DIM + o];
        acc0 += (aggbuf[s0][k] * rd0) * wl + xbuf[s0][k] * wr;
        acc1 += (aggbuf[s1][k] * rd1) * wl + xbuf[s1][k] * wr;
    }
    hbuf[s0][o] = fmaxf(acc0, 0.0f);
    hbuf[s1][o] = fmaxf(acc1, 0.0f);
    __syncthreads();

    // layer-2 projections: g = h@W2l^T (bf16-packed), r = h@W2r^T + b2
    float ga = 0.0f, ra = 0.0f;
    #pragma unroll 4
    for (int m = 0; m < 16; m++) {
        int k = g2 * 16 + m;
        float hv = hbuf[ns][k];
        ga += hv * tW2l[k * OUT_DIM + l];
        ra += hv * tW2r[k * OUT_DIM + l];
    }
    ga += __shfl_xor(ga, 8, 64);  ga += __shfl_xor(ga, 16, 64);
    ra += __shfl_xor(ra, 8, 64);  ra += __shfl_xor(ra, 16, 64);
    if (g2 == 0) {
        gbuf[(size_t)n * OUT_DIM + l] = f2bf(ga);
        rbuf[(size_t)n * OUT_DIM + l] = ra + tb2[l];
    }
}

// ---- Final: out[n] = mean(g_nbr) + r[n]. 8 lanes/node, 4-way ILP
//      (R11-proven loop); gbuf bf16 (1.6MB L2-resident, R12-proven piece). ----
__global__ __launch_bounds__(256) void k_sage3(
    const u16* __restrict__ gbuf, const float* __restrict__ rbuf,
    const int* __restrict__ cnt, const int* __restrict__ slot,
    const u32* __restrict__ xw, void* __restrict__ out)
{
    __shared__ int bfv;
    int t = threadIdx.x;
    if (t < 64) {   // output-dtype probe (proven)
        u32 w = xw[t];
        u32 b = (w >> 8) & 0x7fu;
        ull m2 = __ballot(b >= 0x38u && b <= 0x41u);
        if (t == 0) bfv = (__popcll(m2) >= 56) ? 1 : 0;
    }
    __syncthreads();
    int grp = t >> 3, l = t & 7;
    int n = blockIdx.x * 32 + grp;    // grid = N/32 exactly
    int deg = cnt[n];
    int cl = (deg < CAP) ? deg : CAP;
    const int* srow = slot + (size_t)n * CAP;
    float a0 = 0.0f, a1 = 0.0f, a2 = 0.0f, a3 = 0.0f;
    int j = 0;
    for (; j + 3 < cl; j += 4) {
        int v0 = srow[j];
        int v1 = srow[j + 1];
        int v2 = srow[j + 2];
        int v3 = srow[j + 3];
        a0 += bf2f(gbuf[(size_t)v0 * OUT_DIM + l]);
        a1 += bf2f(gbuf[(size_t)v1 * OUT_DIM + l]);
        a2 += bf2f(gbuf[(size_t)v2 * OUT_DIM + l]);
        a3 += bf2f(gbuf[(size_t)v3 * OUT_DIM + l]);
    }
    for (; j < cl; j++) a0 += bf2f(gbuf[(size_t)srow[j] * OUT_DIM + l]);
    float res = (a0 + a1 + a2 + a3) / fmaxf((float)deg, 1.0f)
              + rbuf[(size_t)n * OUT_DIM + l];
    size_t oi = (size_t)n * OUT_DIM + l;
    if (bfv) ((u16*)out)[oi] = f2bf(res);
    else     ((float*)out)[oi] = res;
}

extern "C" void kernel_launch(void* const* d_in, const int* in_sizes, int n_in,
                              void* d_out, int out_size, void* d_ws, size_t ws_size,
                              hipStream_t stream) {
    const void* x   = d_in[0];
    const int*  ei  = (const int*)d_in[1];
    const void* W1l = d_in[2];
    const void* b1  = d_in[3];
    const void* W1r = d_in[4];
    const void* W2l = d_in[5];
    const void* b2  = d_in[6];
    const void* W2r = d_in[7];

    // ws layout (4B units); total ~40 MB (ws >= 64.4 MB proven in round 2)
    int* qcnt    = (int*)d_ws;                       // 8  (memset target)
    int* cnt     = qcnt + 8;                         // N  (zeroed by k_part)
    float* tW1l  = (float*)(cnt + N_NODES);          // 2048
    float* tW1r  = tW1l + IN_DIM * HID_DIM;          // 2048
    float* tW2l  = tW1r + IN_DIM * HID_DIM;          // 512
    float* tW2r  = tW2l + HID_DIM * OUT_DIM;         // 512
    float* tb1   = tW2r + HID_DIM * OUT_DIM;         // 64
    float* tb2   = tb1 + HID_DIM;                    // 8
    int* slot    = (int*)(tb2 + OUT_DIM);            // N*CAP (25.6 MB)
    u32* qbuf    = (u32*)(slot + (size_t)N_NODES * CAP);       // 8*QCAP (8 MB)
    u16* gbuf    = (u16*)(qbuf + (size_t)8 * QCAP);            // N*8 u16 (1.6 MB)
    float* rbuf  = (float*)(gbuf + (size_t)N_NODES * OUT_DIM); // N*8 f32 (3.2 MB)

    // zero qcnt only (32 B); cnt is zeroed inside k_part
    hipMemsetAsync(d_ws, 0, 8 * sizeof(int), stream);

    k_part<<<NCHUNK, 256, 0, stream>>>(ei, (const u32*)x,
                                       W1l, b1, W1r, W2l, b2, W2r,
                                       qcnt, qbuf, cnt,
                                       tW1l, tW1r, tW2l, tW2r, tb1, tb2);
    k_build2<<<BBLK, 256, 0, stream>>>(qcnt, qbuf, cnt, slot);
    k_sage1<<<N_NODES / 8, 256, 0, stream>>>(x, cnt, slot, tW1l, tW1r,
                                             tW2l, tW2r, tb1, tb2, nullptr,
                                             gbuf, rbuf, (const u32*)x);
    k_sage3<<<N_NODES / 32, 256, 0, stream>>>(gbuf, rbuf, cnt, slot,
                                              (const u32*)x, d_out);
}